// Round 8
// baseline (25.968 us; speedup 1.0000x reference)
//
#include <hip/hip_runtime.h>
#include <stdint.h>

#define BATCHES 64
#define IMG_W 512
#define IMG_ELEMS (512 * 512)
#define PS 8
#define NP 32
#define NPOS_W 505
#define NPOS (505 * 505)
#define TPB 1024           /* one block per batch */
#define F4PT 64            /* float4 loads per thread: 65536/1024 */
#define OUTER 4
#define INNER 16           /* loads in flight per unroll group */
#define NSORT 1024         /* LDS candidate capacity */
#define THR 3.4f

typedef unsigned long long u64;

// Monotone float->uint transform: uint order == float order.
__device__ __forceinline__ unsigned int f2sortable(float f) {
    unsigned int u = __float_as_uint(f);
    return (u & 0x80000000u) ? ~u : (u | 0x80000000u);
}

// Fully fused, one block per batch, ZERO cross-block communication:
//  (1) stream the whole 1 MB image as float4 (16 loads in flight/thread),
//      compacting center values > THR straight into LDS via a block-local
//      LDS atomic counter (no global atomics, no fences — the R2 killers);
//  (2) exact top-32 by O(c^2) rank selection over the ~86 candidates
//      (key = sortable_val<<32 | ~idx reproduces jax top_k order exactly:
//      value desc, lower index first on ties);
//  (3) gather the 32 8x8 patches (image is L1/L2-hot by then).
// Exact in-block fallback if candidate count is outside [32, NSORT]
// (P ~ 1e-40 for N(0,1) data; correctness never depends on the threshold).
__global__ __launch_bounds__(TPB) void patchify_onepass(
    const float* __restrict__ x,
    float* __restrict__ out)
{
    __shared__ u64 skeys[NSORT];
    __shared__ u64 topk[NP];
    __shared__ int lcount;

    const int b = blockIdx.x;
    const int tid = threadIdx.x;
    const float* img = x + (size_t)b * IMG_ELEMS;
    const float4* img4 = (const float4*)img;

    if (tid == 0) lcount = 0;
    __syncthreads();

    // ---- phase 1: stream + compact into LDS ----
#pragma unroll
    for (int mo = 0; mo < OUTER; ++mo) {
        float4 v[INNER];
#pragma unroll
        for (int u = 0; u < INNER; ++u)
            v[u] = img4[(mo * INNER + u) * TPB + tid];
#pragma unroll
        for (int u = 0; u < INNER; ++u) {
            const int f = ((mo * INNER + u) * TPB + tid) << 2;  // flat idx
            const int i = f >> 9;                               // row
            const int j = f & 511;                              // col of elem 0
            const float vv[4] = {v[u].x, v[u].y, v[u].z, v[u].w};
#pragma unroll
            for (int e = 0; e < 4; ++e) {
                const int c = j + e;
                if (vv[e] > THR && i >= 4 && i <= 508 && c >= 4 && c <= 508) {
                    int slot = atomicAdd(&lcount, 1);  // LDS atomic
                    if (slot < NSORT) {
                        unsigned int q =
                            (unsigned int)((i - 4) * NPOS_W + (c - 4));
                        skeys[slot] =
                            ((u64)f2sortable(vv[e]) << 32) | (u64)(~q);
                    }
                }
            }
        }
    }
    __syncthreads();

    const int total = lcount;
    const bool fast = (total >= NP) && (total <= NSORT);

    // ---- phase 2: exact top-32 ----
    if (fast) {
        if (tid < total) {
            const u64 mykey = skeys[tid];
            int rank = 0;
            for (int i = 0; i < total; ++i) rank += (skeys[i] > mykey);
            if (rank < NP) topk[rank] = mykey;  // keys unique -> ranks unique
        }
        __syncthreads();
    } else {
        // exact fallback: 32 rounds of block-wide max below previous key
        u64 prev = ~0ull;
        for (int sel = 0; sel < NP; ++sel) {
            u64 best = 0ull;
            for (int q = tid; q < NPOS; q += TPB) {
                int r = q / NPOS_W;
                int c0 = q - r * NPOS_W;
                float val = img[(r + 4) * IMG_W + (c0 + 4)];
                u64 key = ((u64)f2sortable(val) << 32) | (u64)(~(unsigned int)q);
                if (key < prev && key > best) best = key;
            }
            skeys[tid] = best;
            __syncthreads();
            for (int s = TPB / 2; s > 0; s >>= 1) {
                if (tid < s) {
                    if (skeys[tid + s] > skeys[tid]) skeys[tid] = skeys[tid + s];
                }
                __syncthreads();
            }
            prev = skeys[0];
            if (tid == 0) topk[sel] = prev;
            __syncthreads();
        }
    }

    // ---- phase 3: gather 32 patches x 64 elems (2 per thread) ----
    for (int e = tid; e < NP * PS * PS; e += TPB) {
        int p = e >> 6;
        int rem = e & 63;
        int pi = rem >> 3;
        int pj = rem & 7;
        unsigned int q = ~(unsigned int)(topk[p] & 0xFFFFFFFFull);
        unsigned int r = q / NPOS_W;
        unsigned int c = q - r * NPOS_W;
        out[((size_t)b * NP + p) * (PS * PS) + rem] = img[(r + pi) * IMG_W + (c + pj)];
    }
}

extern "C" void kernel_launch(void* const* d_in, const int* in_sizes, int n_in,
                              void* d_out, int out_size, void* d_ws, size_t ws_size,
                              hipStream_t stream) {
    const float* x = (const float*)d_in[0];
    float* out = (float*)d_out;
    patchify_onepass<<<dim3(BATCHES), dim3(TPB), 0, stream>>>(x, out);
}

// Round 9
// 23.142 us; speedup vs baseline: 1.1221x; 1.1221x over previous
//
#include <hip/hip_runtime.h>
#include <stdint.h>

#define BATCHES 64
#define IMG_W 512
#define IMG_ELEMS (512 * 512)
#define PS 8
#define NP 32
#define NPOS_W 505
#define NPOS (505 * 505)
#define CHUNKS 8           /* blocks per batch in collect */
#define CTPB 512           /* collect threads per block */
#define F4T 16             /* float4 loads per thread: 65536/(8*512) */
#define STPB 512           /* select threads per block */
#define NSORT 512          /* max total candidates for fast path */
#define SEGMAX 64          /* per-chunk candidate segment capacity */
#define THR 3.4f

typedef unsigned long long u64;

// Monotone float->uint transform: uint order == float order.
__device__ __forceinline__ unsigned int f2sortable(float f) {
    unsigned int u = __float_as_uint(f);
    return (u & 0x80000000u) ? ~u : (u | 0x80000000u);
}

// Pass 1: vectorized scan; each (batch,chunk) block compacts center values
// > THR into its OWN disjoint segment using a block-local LDS counter.
// No global atomics (device-scope RMW was the 100us+ killer in R1-R3;
// cross-block fusion refuted both ways: R2 fences 336us, R8 64-CU 41us).
// key = (sortable_val<<32) | ~idx  -> descending key order == jax top_k
// order (value desc, lower index first on ties).
__global__ __launch_bounds__(CTPB) void collect_kernel(
    const float* __restrict__ x,
    int* __restrict__ counts,          /* [BATCHES*CHUNKS] */
    u64* __restrict__ cands,           /* [BATCHES*CHUNKS*seg] */
    int seg)
{
    __shared__ int lcount;
    const int b = blockIdx.x >> 3;
    const int chunk = blockIdx.x & (CHUNKS - 1);
    if (threadIdx.x == 0) lcount = 0;
    __syncthreads();

    const float4* img4 = (const float4*)(x + (size_t)b * IMG_ELEMS);
    const int base = chunk * (CTPB * F4T) + threadIdx.x;
    float4 v[F4T];
#pragma unroll
    for (int k = 0; k < F4T; ++k) v[k] = img4[base + k * CTPB];

    u64* myseg = cands + ((size_t)b * CHUNKS + chunk) * (size_t)seg;

#pragma unroll
    for (int k = 0; k < F4T; ++k) {
        const int f = (base + k * CTPB) << 2;  // flat float index
        const int i = f >> 9;                  // row
        const int j = f & 511;                 // col of element 0
        const float vv[4] = {v[k].x, v[k].y, v[k].z, v[k].w};
#pragma unroll
        for (int e = 0; e < 4; ++e) {
            const int c = j + e;
            if (vv[e] > THR && i >= 4 && i <= 508 && c >= 4 && c <= 508) {
                int slot = atomicAdd(&lcount, 1);   // LDS atomic, block-local
                if (slot < seg) {
                    unsigned int q = (unsigned int)((i - 4) * NPOS_W + (c - 4));
                    myseg[slot] = ((u64)f2sortable(vv[e]) << 32) | (u64)(~q);
                }
            }
        }
    }
    __syncthreads();
    if (threadIdx.x == 0) counts[b * CHUNKS + chunk] = lcount;  // plain store
}

// Pass 2: per batch, concatenate the 8 segments in LDS, exact top-32 by
// O(c^2) rank selection (~86 candidates), then gather the 32 8x8 patches.
// Exact slow fallback if any segment overflowed or total out of range.
__global__ __launch_bounds__(STPB) void select_gather_kernel(
    const float* __restrict__ x,
    const int* __restrict__ counts,
    const u64* __restrict__ cands,
    float* __restrict__ out,
    int seg)
{
    __shared__ u64 skeys[NSORT];
    __shared__ u64 topk[NP];
    __shared__ int cnt[CHUNKS];
    __shared__ int pfx[CHUNKS + 1];
    __shared__ int okf;
    const int b = blockIdx.x;
    const int tid = threadIdx.x;
    const float* img = x + (size_t)b * IMG_ELEMS;

    if (tid < CHUNKS) cnt[tid] = counts[b * CHUNKS + tid];
    if (tid == 0) okf = 1;
    __syncthreads();
    if (tid == 0) {
        int s = 0;
        for (int c = 0; c < CHUNKS; ++c) {
            pfx[c] = s;
            s += cnt[c];
            if (cnt[c] > seg) okf = 0;
        }
        pfx[CHUNKS] = s;
        if (s < NP || s > NSORT) okf = 0;
    }
    __syncthreads();
    const int total = pfx[CHUNKS];
    const bool fast = (okf != 0) && (seg >= 1);

    if (fast) {
        for (int idx = tid; idx < CHUNKS * seg; idx += STPB) {
            int c = idx / seg;
            int i = idx - c * seg;
            if (i < cnt[c])
                skeys[pfx[c] + i] = cands[((size_t)b * CHUNKS + c) * (size_t)seg + i];
        }
        __syncthreads();
        if (tid < total) {
            const u64 mykey = skeys[tid];
            int rank = 0;
            for (int i = 0; i < total; ++i) rank += (skeys[i] > mykey);
            if (rank < NP) topk[rank] = mykey;  // keys unique -> ranks unique
        }
        __syncthreads();
    } else {
        // exact fallback: 32 rounds of block-wide max below previous key
        u64 prev = ~0ull;
        for (int sel = 0; sel < NP; ++sel) {
            u64 best = 0ull;
            for (int q = tid; q < NPOS; q += STPB) {
                int r = q / NPOS_W;
                int c0 = q - r * NPOS_W;
                float val = img[(r + 4) * IMG_W + (c0 + 4)];
                u64 key = ((u64)f2sortable(val) << 32) | (u64)(~(unsigned int)q);
                if (key < prev && key > best) best = key;
            }
            skeys[tid] = best;
            __syncthreads();
            for (int s = STPB / 2; s > 0; s >>= 1) {
                if (tid < s) {
                    if (skeys[tid + s] > skeys[tid]) skeys[tid] = skeys[tid + s];
                }
                __syncthreads();
            }
            prev = skeys[0];
            if (tid == 0) topk[sel] = prev;
            __syncthreads();
        }
    }

    // gather: 32 patches x 64 elems, coalesced writes
    for (int e = tid; e < NP * PS * PS; e += STPB) {
        int p = e >> 6;
        int rem = e & 63;
        int pi = rem >> 3;
        int pj = rem & 7;
        unsigned int q = ~(unsigned int)(topk[p] & 0xFFFFFFFFull);
        unsigned int r = q / NPOS_W;
        unsigned int c = q - r * NPOS_W;
        out[((size_t)b * NP + p) * (PS * PS) + rem] = img[(r + pi) * IMG_W + (c + pj)];
    }
}

extern "C" void kernel_launch(void* const* d_in, const int* in_sizes, int n_in,
                              void* d_out, int out_size, void* d_ws, size_t ws_size,
                              hipStream_t stream) {
    const float* x = (const float*)d_in[0];
    float* out = (float*)d_out;

    int* counts = (int*)d_ws;  // BATCHES*CHUNKS ints = 2 KB
    u64* cands = (u64*)((char*)d_ws + 8192);
    int seg = 0;
    if (ws_size > 8192) {
        size_t s = (ws_size - 8192) / ((size_t)BATCHES * CHUNKS * sizeof(u64));
        seg = (int)(s > (size_t)SEGMAX ? (size_t)SEGMAX : s);
    }

    collect_kernel<<<dim3(BATCHES * CHUNKS), dim3(CTPB), 0, stream>>>(
        x, counts, cands, seg);
    select_gather_kernel<<<dim3(BATCHES), dim3(STPB), 0, stream>>>(
        x, counts, cands, out, seg);
}